// Round 1
// 217.801 us; speedup vs baseline: 1.0808x; 1.0808x over previous
//
#include <hip/hip_runtime.h>

#define NBATCH 8
#define TW 64          // tile width  (output)
#define TH 32          // tile height (output)
#define SROWS 42       // staged rows: image rows -5..36  (TH + 10)
#define SQUADS 20      // staged data quads/row: image cols -8..71 (80 floats)
#define STRDQ 96       // LDS row stride in floats (24 quads; rows are swizzle-rotated)
#define NSTRIP 180     // 20 row-pairs x 9 col-octs (region rows -4..35, cols -4..67)
#define NTHR 192

// ---------------------------------------------------------------------------
// LDS bank-conflict-free layout: logical quad q (0..19) of row R lives at
// physical quad (q + 3*(R>>1)) mod 24. Rationale: inner-loop reads address
// quad 2j+c with row 2rp+r; lane-varying terms (2j, 2rp-derived) are all even
// with the old linear layout, so every wave instruction hit only 4 of the 8
// four-bank groups (16-way phases vs the 8-phase b128 floor; measured
// SQ_LDS_BANK_CONFLICT = 3.2e7 ~= 43% of runtime). The odd per-row-pair
// rotation 3*rp makes the group (2j + 3*rp + const) mod 8 -> all 8 groups.
// Quad-granular permutation is free: each ds_read_b128 is exactly one quad.
// ---------------------------------------------------------------------------
__device__ __forceinline__ int lofs(int R, int q) {   // float offset of (row,quad)
    int p = q + (3 * (R >> 1)) % 24;
    if (p >= 24) p -= 24;
    return R * STRDQ + (p << 2);
}

// accumulate one stencil row: window floats [L, m.x..m.w, R], weights ka,kb,kc
__device__ __forceinline__ void acc_row(float4& v, float L, float4 m, float R,
                                        float ka, float kb, float kc) {
    v.x += ka * L   + kb * m.x + kc * m.y;
    v.y += ka * m.x + kb * m.y + kc * m.z;
    v.z += ka * m.y + kb * m.z + kc * m.w;
    v.w += ka * m.z + kb * m.w + kc * R;
}

// ---------------------------------------------------------------------------
// 5 fused conv3x3+bias+BU+clamp iterations; all 3 pyramid levels, one dispatch.
// One 64x32 output tile per 192-thread block. LDS ping-pong 42x96 x2 = 32.3KB.
// Thread t (<180) owns one 8x2-px strip: 16 ds_read_b128 (4 rows x 4 quads) +
// 4 ds_write_b128 per iteration, all through the swizzled lofs() map.
// Computed region rows -4..35, cols -4..67; validity erodes 1 ring/iter from
// the staged -5..36/-5..68 rim, leaving the exact 64x32 interior after 5
// iters. Out-of-image cells are re-masked to 0 every iter (true zero-pad
// semantics at image edges). clamp via fminf/fmaxf sanitizes garbage/NaN.
// ---------------------------------------------------------------------------
__global__ __launch_bounds__(NTHR, 4) void conv5_all(
    const float* __restrict__ srcU, const float* __restrict__ buU,
    const float* __restrict__ wtU, const float* __restrict__ bsU,
    const float* __restrict__ srcX, const float* __restrict__ buX,
    const float* __restrict__ wtX, const float* __restrict__ bsX,
    const float* __restrict__ srcD, const float* __restrict__ buD,
    const float* __restrict__ wtD, const float* __restrict__ bsD,
    float* __restrict__ dstU, float* __restrict__ dstX, float* __restrict__ dstD)
{
    __shared__ __align__(16) float bufA[SROWS * STRDQ];
    __shared__ __align__(16) float bufB[SROWS * STRDQ];

    const int tid = threadIdx.x;
    const int blk = blockIdx.x;

    const float* src; const float* BU; const float* wt; const float* bs;
    float* dst; int HW; int tx, ty, b;
    if (blk < 4096) {                 // up: 8 x (32 ty x 16 tx)
        src = srcU; BU = buU; wt = wtU; bs = bsU; dst = dstU; HW = 1024;
        b = blk >> 9; int rem = blk & 511; ty = rem >> 4; tx = rem & 15;
    } else if (blk < 5120) {          // x: 8 x (16 ty x 8 tx)
        int t = blk - 4096;
        src = srcX; BU = buX; wt = wtX; bs = bsX; dst = dstX; HW = 512;
        b = t >> 7; int rem = t & 127; ty = rem >> 3; tx = rem & 7;
    } else {                          // down: 8 x (8 ty x 4 tx)
        int t = blk - 5120;
        src = srcD; BU = buD; wt = wtD; bs = bsD; dst = dstD; HW = 256;
        b = t >> 5; int rem = t & 31; ty = rem >> 2; tx = rem & 3;
    }
    const int bh0 = ty * TH, bw0 = tx * TW;
    const long base = (long)b * HW * HW;

    // ---- stage: image rows -5..36, cols -8..71 -> bufA (img col c -> data quad (c+8)/4)
    for (int s = tid; s < SROWS * SQUADS; s += NTHR) {
        int r = s / SQUADS, cq = s - r * SQUADS;
        int gh = bh0 + r - 5;
        int gw = bw0 + (cq << 2) - 8;
        float4 v = {0.0f, 0.0f, 0.0f, 0.0f};
        if ((unsigned)gh < (unsigned)HW) {
            const float* gp = src + base + (long)gh * HW + gw;
            if (gw >= 0 && gw + 3 < HW) {
                v = *(const float4*)gp;
            } else {
                if ((unsigned)(gw + 0) < (unsigned)HW) v.x = gp[0];
                if ((unsigned)(gw + 1) < (unsigned)HW) v.y = gp[1];
                if ((unsigned)(gw + 2) < (unsigned)HW) v.z = gp[2];
                if ((unsigned)(gw + 3) < (unsigned)HW) v.w = gp[3];
            }
        }
        *(float4*)&bufA[lofs(r, cq)] = v;
    }

    const float k00 = wt[0], k01 = wt[1], k02 = wt[2];
    const float k10 = wt[3], k11 = wt[4], k12 = wt[5];
    const float k20 = wt[6], k21 = wt[7], k22 = wt[8];
    const float bias = bs[0];

    // ---- per-thread strip setup (strip s=tid: rp=s/9 row-pair, j=s%9 col-oct)
    // outputs: image rows 2rp-4+i (i=0,1), cols 8j-4+k (k=0..7)
    // window: buffer rows 2rp..2rp+3, logical quads 2j..2j+3
    const bool act = (tid < NSTRIP);
    int sc = act ? tid : 0;
    int rp = sc / 9, j = sc - rp * 9;

    // precomputed swizzled LDS offsets (constant across all 5 iterations)
    int rdo[4][4];
    #pragma unroll
    for (int r = 0; r < 4; ++r)
        #pragma unroll
        for (int c = 0; c < 4; ++c)
            rdo[r][c] = lofs(2 * rp + r, 2 * j + c);
    int wro[2][2];
    #pragma unroll
    for (int i = 0; i < 2; ++i) {
        wro[i][0] = lofs(2 * rp + 1 + i, 2 * j + 1);
        wro[i][1] = lofs(2 * rp + 1 + i, 2 * j + 2);
    }

    float4 wf0, wf1;                  // column in-image masks (k=0..3, 4..7)
    {
        float* p0 = (float*)&wf0; float* p1 = (float*)&wf1;
        #pragma unroll
        for (int k = 0; k < 4; ++k) {
            p0[k] = ((unsigned)(bw0 + 8 * j - 4 + k) < (unsigned)HW) ? 1.0f : 0.0f;
            p1[k] = ((unsigned)(bw0 + 8 * j + k)     < (unsigned)HW) ? 1.0f : 0.0f;
        }
    }
    float hf[2];
    float4 bu0[2], bu1[2];            // (BU + bias), pre-masked 0 outside image
    #pragma unroll
    for (int i = 0; i < 2; ++i) {
        int gh = bh0 + 2 * rp - 4 + i;
        bool hok = act && ((unsigned)gh < (unsigned)HW);
        hf[i] = hok ? 1.0f : 0.0f;
        int gw0 = bw0 + 8 * j - 4;    // 4-aligned
        const float* bp = BU + base + (long)gh * HW + gw0;
        if (hok && gw0 >= 0 && gw0 + 7 < HW) {
            // interior fast path: two aligned float4 loads
            float4 a = *(const float4*)bp;
            float4 c = *(const float4*)(bp + 4);
            bu0[i] = {a.x + bias, a.y + bias, a.z + bias, a.w + bias};
            bu1[i] = {c.x + bias, c.y + bias, c.z + bias, c.w + bias};
        } else {
            float* b0 = (float*)&bu0[i]; float* b1 = (float*)&bu1[i];
            #pragma unroll
            for (int k = 0; k < 4; ++k) {
                int w0 = gw0 + k;
                int w1 = gw0 + 4 + k;
                b0[k] = (hok && (unsigned)w0 < (unsigned)HW) ? (bp[k] + bias)     : 0.0f;
                b1[k] = (hok && (unsigned)w1 < (unsigned)HW) ? (bp[k + 4] + bias) : 0.0f;
            }
        }
    }

    float* cur = bufA;
    float* nxt = bufB;

    for (int it = 0; it < 5; ++it) {
        __syncthreads();
        if (act) {
            float4 q[4][4];
            #pragma unroll
            for (int r = 0; r < 4; ++r)
                #pragma unroll
                for (int c = 0; c < 4; ++c)
                    q[r][c] = *(const float4*)(cur + rdo[r][c]);
            #pragma unroll
            for (int i = 0; i < 2; ++i) {
                float4 v0 = bu0[i];
                float4 v1 = bu1[i];
                acc_row(v0, q[i][0].w,     q[i][1],     q[i][2].x,     k00, k01, k02);
                acc_row(v0, q[i + 1][0].w, q[i + 1][1], q[i + 1][2].x, k10, k11, k12);
                acc_row(v0, q[i + 2][0].w, q[i + 2][1], q[i + 2][2].x, k20, k21, k22);
                acc_row(v1, q[i][1].w,     q[i][2],     q[i][3].x,     k00, k01, k02);
                acc_row(v1, q[i + 1][1].w, q[i + 1][2], q[i + 1][3].x, k10, k11, k12);
                acc_row(v1, q[i + 2][1].w, q[i + 2][2], q[i + 2][3].x, k20, k21, k22);
                float m = hf[i];
                v0.x = fminf(1.0f, fmaxf(-1.0f, v0.x)) * (m * wf0.x);
                v0.y = fminf(1.0f, fmaxf(-1.0f, v0.y)) * (m * wf0.y);
                v0.z = fminf(1.0f, fmaxf(-1.0f, v0.z)) * (m * wf0.z);
                v0.w = fminf(1.0f, fmaxf(-1.0f, v0.w)) * (m * wf0.w);
                v1.x = fminf(1.0f, fmaxf(-1.0f, v1.x)) * (m * wf1.x);
                v1.y = fminf(1.0f, fmaxf(-1.0f, v1.y)) * (m * wf1.y);
                v1.z = fminf(1.0f, fmaxf(-1.0f, v1.z)) * (m * wf1.z);
                v1.w = fminf(1.0f, fmaxf(-1.0f, v1.w)) * (m * wf1.w);
                *(float4*)(nxt + wro[i][0]) = v0;
                *(float4*)(nxt + wro[i][1]) = v1;
            }
        }
        float* t = cur; cur = nxt; nxt = t;
    }
    __syncthreads();

    // ---- store 64x32 interior: image (r,c) -> buffer (r+5, data quad (c+8)/4)
    for (int i2 = tid; i2 < TH * (TW / 4); i2 += NTHR) {
        int r = i2 >> 4;
        int cq = i2 & 15;
        float4 v = *(const float4*)&cur[lofs(r + 5, cq + 2)];
        *(float4*)&dst[base + (long)(bh0 + r) * HW + bw0 + (cq << 2)] = v;
    }
}

// ---------------------------------------------------------------------------
// Cross-scale 1x1-conv fusion: one thread per down-level pixel; U/X/D read
// exactly once, all three outputs written.
// ---------------------------------------------------------------------------
__global__ __launch_bounds__(256) void fuse_all(
    const float* __restrict__ X,   // 8 x 512^2
    const float* __restrict__ D,   // 8 x 256^2
    const float* __restrict__ U,   // 8 x 1024^2
    const float* __restrict__ cx,
    const float* __restrict__ cd,
    const float* __restrict__ cu,
    float* __restrict__ xo, float* __restrict__ dno, float* __restrict__ upo)
{
    const int total = NBATCH << 16;  // 8*256*256
    int idx = blockIdx.x * blockDim.x + threadIdx.x;
    if (idx >= total) return;
    int wd = idx & 255;
    int hd = (idx >> 8) & 255;
    int b  = idx >> 16;

    const float cx0 = cx[0], cx1 = cx[1], cx2 = cx[2];
    const float cd0 = cd[0], cd1 = cd[1], cd2 = cd[2];
    const float cu0 = cu[0], cu1 = cu[1], cu2 = cu[2];

    int ub = (b << 20) + ((hd << 2) << 10) + (wd << 2);
    float4 u0 = *(const float4*)&U[ub];
    float4 u1 = *(const float4*)&U[ub + 1024];
    float4 u2 = *(const float4*)&U[ub + 2048];
    float4 u3 = *(const float4*)&U[ub + 3072];
    int xb = (b << 18) + ((hd << 1) << 9) + (wd << 1);
    float2 x0 = *(const float2*)&X[xb];
    float2 x1 = *(const float2*)&X[xb + 512];
    float dv = D[idx];

    float p00 = 0.25f * (u0.x + u0.y + u1.x + u1.y);
    float p01 = 0.25f * (u0.z + u0.w + u1.z + u1.w);
    float p10 = 0.25f * (u2.x + u2.y + u3.x + u3.y);
    float p11 = 0.25f * (u2.z + u2.w + u3.z + u3.w);
    float pu4 = 0.25f * (p00 + p01 + p10 + p11);
    float px2 = 0.25f * (x0.x + x0.y + x1.x + x1.y);

    dno[idx] = cd0 * pu4 + cd1 * px2 + cd2 * dv;

    float2 xo0, xo1;
    xo0.x = cx0 * p00 + cx1 * x0.x + cx2 * dv;
    xo0.y = cx0 * p01 + cx1 * x0.y + cx2 * dv;
    xo1.x = cx0 * p10 + cx1 * x1.x + cx2 * dv;
    xo1.y = cx0 * p11 + cx1 * x1.y + cx2 * dv;
    *(float2*)&xo[xb]       = xo0;
    *(float2*)&xo[xb + 512] = xo1;

    float4 o0, o1, o2, o3;
    o0.x = cu0 * u0.x + cu1 * x0.x + cu2 * dv;
    o0.y = cu0 * u0.y + cu1 * x0.x + cu2 * dv;
    o0.z = cu0 * u0.z + cu1 * x0.y + cu2 * dv;
    o0.w = cu0 * u0.w + cu1 * x0.y + cu2 * dv;
    o1.x = cu0 * u1.x + cu1 * x0.x + cu2 * dv;
    o1.y = cu0 * u1.y + cu1 * x0.x + cu2 * dv;
    o1.z = cu0 * u1.z + cu1 * x0.y + cu2 * dv;
    o1.w = cu0 * u1.w + cu1 * x0.y + cu2 * dv;
    o2.x = cu0 * u2.x + cu1 * x1.x + cu2 * dv;
    o2.y = cu0 * u2.y + cu1 * x1.x + cu2 * dv;
    o2.z = cu0 * u2.z + cu1 * x1.y + cu2 * dv;
    o2.w = cu0 * u2.w + cu1 * x1.y + cu2 * dv;
    o3.x = cu0 * u3.x + cu1 * x1.x + cu2 * dv;
    o3.y = cu0 * u3.y + cu1 * x1.x + cu2 * dv;
    o3.z = cu0 * u3.z + cu1 * x1.y + cu2 * dv;
    o3.w = cu0 * u3.w + cu1 * x1.y + cu2 * dv;
    *(float4*)&upo[ub]        = o0;
    *(float4*)&upo[ub + 1024] = o1;
    *(float4*)&upo[ub + 2048] = o2;
    *(float4*)&upo[ub + 3072] = o3;
}

// ---------------------------------------------------------------------------
extern "C" void kernel_launch(void* const* d_in, const int* in_sizes, int n_in,
                              void* d_out, int out_size, void* d_ws, size_t ws_size,
                              hipStream_t stream)
{
    const float* x    = (const float*)d_in[0];
    const float* down = (const float*)d_in[1];
    const float* up   = (const float*)d_in[2];
    const float* BUx  = (const float*)d_in[3];
    const float* BUd  = (const float*)d_in[4];
    const float* BUu  = (const float*)d_in[5];
    const float* wAx  = (const float*)d_in[6];
    const float* bx   = (const float*)d_in[7];
    const float* wAd  = (const float*)d_in[8];
    const float* bd   = (const float*)d_in[9];
    const float* wAu  = (const float*)d_in[10];
    const float* bu   = (const float*)d_in[11];
    const float* c1x  = (const float*)d_in[12];
    const float* c1d  = (const float*)d_in[13];
    const float* c1u  = (const float*)d_in[14];

    float* out = (float*)d_out;
    float* ws  = (float*)d_ws;

    const int NX = NBATCH * 512 * 512;
    const int ND = NBATCH * 256 * 256;

    float* wsX = ws;
    float* wsD = ws + NX;
    float* wsU = ws + NX + ND;
    float* outX = out;
    float* outD = out + NX;
    float* outU = out + NX + ND;

    // one dispatch, all levels: 4096 up + 1024 x + 256 down tiles (64x32 each)
    conv5_all<<<5376, NTHR, 0, stream>>>(
        up,   BUu, wAu, bu,
        x,    BUx, wAx, bx,
        down, BUd, wAd, bd,
        wsU, wsX, wsD);

    fuse_all<<<(ND + 255) / 256, 256, 0, stream>>>(wsX, wsD, wsU, c1x, c1d, c1u,
                                                   outX, outD, outU);
}

// Round 2
// 212.100 us; speedup vs baseline: 1.1099x; 1.0269x over previous
//
#include <hip/hip_runtime.h>

#define NBATCH 8
#define TW 64          // tile width  (output)
#define TH 32          // tile height (output)
#define SROWS 42       // staged rows: image rows -5..36  (TH + 10)
#define SQUADS 20      // staged data quads/row: image cols -8..71 (80 floats)
#define STRDQ 96       // LDS row stride in floats (24 quads; rows are swizzle-rotated)
#define NSTRIP 180     // 20 row-pairs x 9 col-octs (region rows -4..35, cols -4..67)
#define NTHR 192
// LDS: buffer A = 42 rows (staged -5..36). Buffer B only ever holds written
// rows R=1..41-read-rim; B is allocated 41 rows starting right after A, with
// its phantom row R=0 aliasing A's row 41 (stale/garbage reads there are part
// of the eroded rim, clamp-sanitized — identical semantics to the previous
// uninitialized-bufB-rim behavior). Total (42+41)*96*4 = 31872 B -> 5 blk/CU.
#define LDSFLOATS (83 * STRDQ)

// ---------------------------------------------------------------------------
// LDS bank-conflict-free layout: logical quad q (0..19) of row R lives at
// physical quad (q + 3*(R>>1)) mod 24, so a read of (row 2rp+r, quad 2j+c)
// hits 4-bank group (2j + 3rp + const) mod 8. The strip->thread map below is
// chosen so every wave instruction has EXACTLY 8 lanes per group (the
// natural rp=tid/9 map gives 9/9/9/9/7/7/7/7 -> ~6 extra LDS cycles/op,
// measured 1.02e7 SQ_LDS_BANK_CONFLICT).
// ---------------------------------------------------------------------------
__device__ __forceinline__ int lofs(int R, int q) {   // float offset of (row,quad)
    int p = q + (3 * (R >> 1)) % 24;
    if (p >= 24) p -= 24;
    return R * STRDQ + (p << 2);
}

// accumulate one stencil row: window floats [L, m.x..m.w, R], weights ka,kb,kc
__device__ __forceinline__ void acc_row(float4& v, float L, float4 m, float R,
                                        float ka, float kb, float kc) {
    v.x += ka * L   + kb * m.x + kc * m.y;
    v.y += ka * m.x + kb * m.y + kc * m.z;
    v.z += ka * m.y + kb * m.z + kc * m.w;
    v.w += ka * m.z + kb * m.w + kc * R;
}

// ---------------------------------------------------------------------------
// 5 fused conv3x3+bias+BU+clamp iterations; all 3 pyramid levels, one dispatch.
// One 64x32 output tile per 192-thread block. LDS ping-pong 31.9KB (5 blk/CU).
// Thread t (<180) owns one 8x2-px strip: 16 ds_read_b128 + 4 ds_write_b128
// per iteration through the swizzled lofs() map, bank-balanced per wave via
// the group-round-robin strip assignment. Computed region rows -4..35, cols
// -4..67; validity erodes 1 ring/iter, leaving the exact 64x32 interior after
// 5 iters. Out-of-image cells re-masked to 0 every iter (true zero-pad
// semantics). clamp via fminf/fmaxf sanitizes garbage/NaN rim reads.
// ---------------------------------------------------------------------------
__global__ __launch_bounds__(NTHR, 4) void conv5_all(
    const float* __restrict__ srcU, const float* __restrict__ buU,
    const float* __restrict__ wtU, const float* __restrict__ bsU,
    const float* __restrict__ srcX, const float* __restrict__ buX,
    const float* __restrict__ wtX, const float* __restrict__ bsX,
    const float* __restrict__ srcD, const float* __restrict__ buD,
    const float* __restrict__ wtD, const float* __restrict__ bsD,
    float* __restrict__ dstU, float* __restrict__ dstX, float* __restrict__ dstD)
{
    __shared__ __align__(16) float smem[LDSFLOATS];
    float* const pA = smem;            // rows R=0..41 at lofs(R,q)
    float* const pB = smem + 3936;     // rows R=1..41 at lofs(R,q); R=0 aliases A row 41

    const int tid = threadIdx.x;
    const int blk = blockIdx.x;

    const float* src; const float* BU; const float* wt; const float* bs;
    float* dst; int HW; int tx, ty, b;
    if (blk < 4096) {                 // up: 8 x (32 ty x 16 tx)
        src = srcU; BU = buU; wt = wtU; bs = bsU; dst = dstU; HW = 1024;
        b = blk >> 9; int rem = blk & 511; ty = rem >> 4; tx = rem & 15;
    } else if (blk < 5120) {          // x: 8 x (16 ty x 8 tx)
        int t = blk - 4096;
        src = srcX; BU = buX; wt = wtX; bs = bsX; dst = dstX; HW = 512;
        b = t >> 7; int rem = t & 127; ty = rem >> 3; tx = rem & 7;
    } else {                          // down: 8 x (8 ty x 4 tx)
        int t = blk - 5120;
        src = srcD; BU = buD; wt = wtD; bs = bsD; dst = dstD; HW = 256;
        b = t >> 5; int rem = t & 31; ty = rem >> 2; tx = rem & 3;
    }
    const int bh0 = ty * TH, bw0 = tx * TW;
    const long base = (long)b * HW * HW;

    // ---- stage: image rows -5..36, cols -8..71 -> pA (img col c -> data quad (c+8)/4)
    for (int s = tid; s < SROWS * SQUADS; s += NTHR) {
        int r = s / SQUADS, cq = s - r * SQUADS;
        int gh = bh0 + r - 5;
        int gw = bw0 + (cq << 2) - 8;
        float4 v = {0.0f, 0.0f, 0.0f, 0.0f};
        if ((unsigned)gh < (unsigned)HW) {
            const float* gp = src + base + (long)gh * HW + gw;
            if (gw >= 0 && gw + 3 < HW) {
                v = *(const float4*)gp;
            } else {
                if ((unsigned)(gw + 0) < (unsigned)HW) v.x = gp[0];
                if ((unsigned)(gw + 1) < (unsigned)HW) v.y = gp[1];
                if ((unsigned)(gw + 2) < (unsigned)HW) v.z = gp[2];
                if ((unsigned)(gw + 3) < (unsigned)HW) v.w = gp[3];
            }
        }
        *(float4*)&pA[lofs(r, cq)] = v;
    }

    const float k00 = wt[0], k01 = wt[1], k02 = wt[2];
    const float k10 = wt[3], k11 = wt[4], k12 = wt[5];
    const float k20 = wt[6], k21 = wt[7], k22 = wt[8];
    const float bias = bs[0];

    // ---- strip assignment: thread t -> (t>>3)-th strip of bank-group
    // posmap[t&7]. Groups {0,1,3,6} have 23 strips (-> thread positions 0..3,
    // 23 threads each), groups {2,4,5,7} have 22 (-> positions 4..7). Within
    // row-pair rp, strips of group g exist iff rp parity == g parity, at
    // j = j0 + 4*m (j0 = ((g-3rp)&7)>>1; m = 0..2 if j0==0 else 0..1).
    const bool act = (tid < NSTRIP);
    int rp = 0, j = 0;
    {
        int g = (0x75426310u >> ((tid & 7) << 2)) & 0xF;  // posmap {0,1,3,6,2,4,5,7}
        int need = tid >> 3;
        for (int r_ = (g & 1); r_ < 20; r_ += 2) {
            int j0 = ((g - 3 * r_) & 7) >> 1;             // 0..3
            int c = (j0 == 0) ? 3 : 2;
            if (need < c) { rp = r_; j = j0 + 4 * need; break; }
            need -= c;
        }
    }

    // precomputed swizzled LDS offsets (valid for both pA and pB bases)
    int rdo[4][4];
    #pragma unroll
    for (int r = 0; r < 4; ++r)
        #pragma unroll
        for (int c = 0; c < 4; ++c)
            rdo[r][c] = lofs(2 * rp + r, 2 * j + c);
    int wro[2][2];
    #pragma unroll
    for (int i = 0; i < 2; ++i) {
        wro[i][0] = lofs(2 * rp + 1 + i, 2 * j + 1);
        wro[i][1] = lofs(2 * rp + 1 + i, 2 * j + 2);
    }

    float4 wf0, wf1;                  // column in-image masks (k=0..3, 4..7)
    {
        float* p0 = (float*)&wf0; float* p1 = (float*)&wf1;
        #pragma unroll
        for (int k = 0; k < 4; ++k) {
            p0[k] = ((unsigned)(bw0 + 8 * j - 4 + k) < (unsigned)HW) ? 1.0f : 0.0f;
            p1[k] = ((unsigned)(bw0 + 8 * j + k)     < (unsigned)HW) ? 1.0f : 0.0f;
        }
    }
    float hf[2];
    float4 bu0[2], bu1[2];            // (BU + bias), pre-masked 0 outside image
    #pragma unroll
    for (int i = 0; i < 2; ++i) {
        int gh = bh0 + 2 * rp - 4 + i;
        bool hok = act && ((unsigned)gh < (unsigned)HW);
        hf[i] = hok ? 1.0f : 0.0f;
        int gw0 = bw0 + 8 * j - 4;    // 4-aligned
        const float* bp = BU + base + (long)gh * HW + gw0;
        if (hok && gw0 >= 0 && gw0 + 7 < HW) {
            // interior fast path: two aligned float4 loads
            float4 a = *(const float4*)bp;
            float4 c = *(const float4*)(bp + 4);
            bu0[i] = {a.x + bias, a.y + bias, a.z + bias, a.w + bias};
            bu1[i] = {c.x + bias, c.y + bias, c.z + bias, c.w + bias};
        } else {
            float* b0 = (float*)&bu0[i]; float* b1 = (float*)&bu1[i];
            #pragma unroll
            for (int k = 0; k < 4; ++k) {
                int w0 = gw0 + k;
                int w1 = gw0 + 4 + k;
                b0[k] = (hok && (unsigned)w0 < (unsigned)HW) ? (bp[k] + bias)     : 0.0f;
                b1[k] = (hok && (unsigned)w1 < (unsigned)HW) ? (bp[k + 4] + bias) : 0.0f;
            }
        }
    }

    float* cur = pA;
    float* nxt = pB;

    for (int it = 0; it < 5; ++it) {
        __syncthreads();
        if (act) {
            float4 q[4][4];
            #pragma unroll
            for (int r = 0; r < 4; ++r)
                #pragma unroll
                for (int c = 0; c < 4; ++c)
                    q[r][c] = *(const float4*)(cur + rdo[r][c]);
            #pragma unroll
            for (int i = 0; i < 2; ++i) {
                float4 v0 = bu0[i];
                float4 v1 = bu1[i];
                acc_row(v0, q[i][0].w,     q[i][1],     q[i][2].x,     k00, k01, k02);
                acc_row(v0, q[i + 1][0].w, q[i + 1][1], q[i + 1][2].x, k10, k11, k12);
                acc_row(v0, q[i + 2][0].w, q[i + 2][1], q[i + 2][2].x, k20, k21, k22);
                acc_row(v1, q[i][1].w,     q[i][2],     q[i][3].x,     k00, k01, k02);
                acc_row(v1, q[i + 1][1].w, q[i + 1][2], q[i + 1][3].x, k10, k11, k12);
                acc_row(v1, q[i + 2][1].w, q[i + 2][2], q[i + 2][3].x, k20, k21, k22);
                float m = hf[i];
                v0.x = fminf(1.0f, fmaxf(-1.0f, v0.x)) * (m * wf0.x);
                v0.y = fminf(1.0f, fmaxf(-1.0f, v0.y)) * (m * wf0.y);
                v0.z = fminf(1.0f, fmaxf(-1.0f, v0.z)) * (m * wf0.z);
                v0.w = fminf(1.0f, fmaxf(-1.0f, v0.w)) * (m * wf0.w);
                v1.x = fminf(1.0f, fmaxf(-1.0f, v1.x)) * (m * wf1.x);
                v1.y = fminf(1.0f, fmaxf(-1.0f, v1.y)) * (m * wf1.y);
                v1.z = fminf(1.0f, fmaxf(-1.0f, v1.z)) * (m * wf1.z);
                v1.w = fminf(1.0f, fmaxf(-1.0f, v1.w)) * (m * wf1.w);
                *(float4*)(nxt + wro[i][0]) = v0;
                *(float4*)(nxt + wro[i][1]) = v1;
            }
        }
        float* t = cur; cur = nxt; nxt = t;
    }
    __syncthreads();

    // ---- store 64x32 interior from pB (cur after 5 swaps): image (r,c) ->
    // row r+5, data quad (c+8)/4 (R in 5..36, all within B's written range)
    for (int i2 = tid; i2 < TH * (TW / 4); i2 += NTHR) {
        int r = i2 >> 4;
        int cq = i2 & 15;
        float4 v = *(const float4*)&cur[lofs(r + 5, cq + 2)];
        *(float4*)&dst[base + (long)(bh0 + r) * HW + bw0 + (cq << 2)] = v;
    }
}

// ---------------------------------------------------------------------------
// Cross-scale 1x1-conv fusion: one thread per down-level pixel; U/X/D read
// exactly once, all three outputs written.
// ---------------------------------------------------------------------------
__global__ __launch_bounds__(256) void fuse_all(
    const float* __restrict__ X,   // 8 x 512^2
    const float* __restrict__ D,   // 8 x 256^2
    const float* __restrict__ U,   // 8 x 1024^2
    const float* __restrict__ cx,
    const float* __restrict__ cd,
    const float* __restrict__ cu,
    float* __restrict__ xo, float* __restrict__ dno, float* __restrict__ upo)
{
    const int total = NBATCH << 16;  // 8*256*256
    int idx = blockIdx.x * blockDim.x + threadIdx.x;
    if (idx >= total) return;
    int wd = idx & 255;
    int hd = (idx >> 8) & 255;
    int b  = idx >> 16;

    const float cx0 = cx[0], cx1 = cx[1], cx2 = cx[2];
    const float cd0 = cd[0], cd1 = cd[1], cd2 = cd[2];
    const float cu0 = cu[0], cu1 = cu[1], cu2 = cu[2];

    int ub = (b << 20) + ((hd << 2) << 10) + (wd << 2);
    float4 u0 = *(const float4*)&U[ub];
    float4 u1 = *(const float4*)&U[ub + 1024];
    float4 u2 = *(const float4*)&U[ub + 2048];
    float4 u3 = *(const float4*)&U[ub + 3072];
    int xb = (b << 18) + ((hd << 1) << 9) + (wd << 1);
    float2 x0 = *(const float2*)&X[xb];
    float2 x1 = *(const float2*)&X[xb + 512];
    float dv = D[idx];

    float p00 = 0.25f * (u0.x + u0.y + u1.x + u1.y);
    float p01 = 0.25f * (u0.z + u0.w + u1.z + u1.w);
    float p10 = 0.25f * (u2.x + u2.y + u3.x + u3.y);
    float p11 = 0.25f * (u2.z + u2.w + u3.z + u3.w);
    float pu4 = 0.25f * (p00 + p01 + p10 + p11);
    float px2 = 0.25f * (x0.x + x0.y + x1.x + x1.y);

    dno[idx] = cd0 * pu4 + cd1 * px2 + cd2 * dv;

    float2 xo0, xo1;
    xo0.x = cx0 * p00 + cx1 * x0.x + cx2 * dv;
    xo0.y = cx0 * p01 + cx1 * x0.y + cx2 * dv;
    xo1.x = cx0 * p10 + cx1 * x1.x + cx2 * dv;
    xo1.y = cx0 * p11 + cx1 * x1.y + cx2 * dv;
    *(float2*)&xo[xb]       = xo0;
    *(float2*)&xo[xb + 512] = xo1;

    float4 o0, o1, o2, o3;
    o0.x = cu0 * u0.x + cu1 * x0.x + cu2 * dv;
    o0.y = cu0 * u0.y + cu1 * x0.x + cu2 * dv;
    o0.z = cu0 * u0.z + cu1 * x0.y + cu2 * dv;
    o0.w = cu0 * u0.w + cu1 * x0.y + cu2 * dv;
    o1.x = cu0 * u1.x + cu1 * x0.x + cu2 * dv;
    o1.y = cu0 * u1.y + cu1 * x0.x + cu2 * dv;
    o1.z = cu0 * u1.z + cu1 * x0.y + cu2 * dv;
    o1.w = cu0 * u1.w + cu1 * x0.y + cu2 * dv;
    o2.x = cu0 * u2.x + cu1 * x1.x + cu2 * dv;
    o2.y = cu0 * u2.y + cu1 * x1.x + cu2 * dv;
    o2.z = cu0 * u2.z + cu1 * x1.y + cu2 * dv;
    o2.w = cu0 * u2.w + cu1 * x1.y + cu2 * dv;
    o3.x = cu0 * u3.x + cu1 * x1.x + cu2 * dv;
    o3.y = cu0 * u3.y + cu1 * x1.x + cu2 * dv;
    o3.z = cu0 * u3.z + cu1 * x1.y + cu2 * dv;
    o3.w = cu0 * u3.w + cu1 * x1.y + cu2 * dv;
    *(float4*)&upo[ub]        = o0;
    *(float4*)&upo[ub + 1024] = o1;
    *(float4*)&upo[ub + 2048] = o2;
    *(float4*)&upo[ub + 3072] = o3;
}

// ---------------------------------------------------------------------------
extern "C" void kernel_launch(void* const* d_in, const int* in_sizes, int n_in,
                              void* d_out, int out_size, void* d_ws, size_t ws_size,
                              hipStream_t stream)
{
    const float* x    = (const float*)d_in[0];
    const float* down = (const float*)d_in[1];
    const float* up   = (const float*)d_in[2];
    const float* BUx  = (const float*)d_in[3];
    const float* BUd  = (const float*)d_in[4];
    const float* BUu  = (const float*)d_in[5];
    const float* wAx  = (const float*)d_in[6];
    const float* bx   = (const float*)d_in[7];
    const float* wAd  = (const float*)d_in[8];
    const float* bd   = (const float*)d_in[9];
    const float* wAu  = (const float*)d_in[10];
    const float* bu   = (const float*)d_in[11];
    const float* c1x  = (const float*)d_in[12];
    const float* c1d  = (const float*)d_in[13];
    const float* c1u  = (const float*)d_in[14];

    float* out = (float*)d_out;
    float* ws  = (float*)d_ws;

    const int NX = NBATCH * 512 * 512;
    const int ND = NBATCH * 256 * 256;

    float* wsX = ws;
    float* wsD = ws + NX;
    float* wsU = ws + NX + ND;
    float* outX = out;
    float* outD = out + NX;
    float* outU = out + NX + ND;

    // one dispatch, all levels: 4096 up + 1024 x + 256 down tiles (64x32 each)
    conv5_all<<<5376, NTHR, 0, stream>>>(
        up,   BUu, wAu, bu,
        x,    BUx, wAx, bx,
        down, BUd, wAd, bd,
        wsU, wsX, wsD);

    fuse_all<<<(ND + 255) / 256, 256, 0, stream>>>(wsX, wsD, wsU, c1x, c1d, c1u,
                                                   outX, outD, outU);
}

// Round 3
// 208.419 us; speedup vs baseline: 1.1295x; 1.0177x over previous
//
#include <hip/hip_runtime.h>

#define NBATCH 8
#define TW 64          // tile width  (output)
#define TH 32          // tile height (output)
#define SROWS 42       // staged rows: image rows -5..36  (TH + 10)
#define SQUADS 20      // staged data quads/row: image cols -8..71 (80 floats)
#define STRDQ 80       // LDS row stride in floats (20 quads, rotation mod 20)
#define NSTRIP 180     // 20 row-pairs x 9 col-octs (region rows -4..35, cols -4..67)
#define NTHR 192
// LDS: two full 42-row buffers @ 80 floats = 26880 B -> rounds to 27136 ->
// floor(163840/27136) = 6 blocks/CU (18 waves) vs 5 at the previous 32256.

// ---------------------------------------------------------------------------
// Swizzled LDS layout: logical quad q (0..19) of row R lives at physical quad
// (q + 3*(R>>1)) mod 20. Bank 4-group of an access = (4R + p) mod 8; the
// mod-20 wrap adds a lane-dependent +4 perturbation (20 = 4 mod 8), so the
// posmap lane balance below is approximate rather than exact -- measured
// calibration (R0..R2) shows the counter's baseline dominates at this level
// and LDS pipe has headroom (~33% busy). Chosen to fit 6 blocks/CU.
// ---------------------------------------------------------------------------
__device__ __forceinline__ int lofs(int R, int q) {   // float offset of (row,quad)
    int rot = (3 * (R >> 1)) % 20;
    int p = q + rot;
    if (p >= 20) p -= 20;
    return R * STRDQ + (p << 2);
}

// accumulate one stencil row: window floats [L, m.x..m.w, R], weights ka,kb,kc
__device__ __forceinline__ void acc_row(float4& v, float L, float4 m, float R,
                                        float ka, float kb, float kc) {
    v.x += ka * L   + kb * m.x + kc * m.y;
    v.y += ka * m.x + kb * m.y + kc * m.z;
    v.z += ka * m.y + kb * m.z + kc * m.w;
    v.w += ka * m.z + kb * m.w + kc * R;
}

// clamp to [-1,1] then apply precomputed mask; all LDS inputs are finite by
// construction (A fully staged, B written-or-zeroed), so fmed3 NaN semantics
// never engage and out-of-image padding cells stay exactly 0.
__device__ __forceinline__ void clamp_mask(float4& v, float4 pm) {
    v.x = __builtin_amdgcn_fmed3f(v.x, -1.0f, 1.0f) * pm.x;
    v.y = __builtin_amdgcn_fmed3f(v.y, -1.0f, 1.0f) * pm.y;
    v.z = __builtin_amdgcn_fmed3f(v.z, -1.0f, 1.0f) * pm.z;
    v.w = __builtin_amdgcn_fmed3f(v.w, -1.0f, 1.0f) * pm.w;
}

// ---------------------------------------------------------------------------
// 5 fused conv3x3+bias+BU+clamp iterations; all 3 pyramid levels, one dispatch.
// One 64x32 output tile per 192-thread block. LDS ping-pong 26.9KB (6 blk/CU).
// Thread t (<180) owns one 8x2-px strip: 16 ds_read_b128 + 4 ds_write_b128
// per iteration through the swizzled lofs() map. Computed region rows -4..35,
// cols -4..67; validity erodes 1 ring/iter, leaving the exact 64x32 interior
// after 5 iters. Out-of-image cells re-masked to 0 every iter (true zero-pad
// semantics at image edges).
// ---------------------------------------------------------------------------
__global__ __launch_bounds__(NTHR, 4) void conv5_all(
    const float* __restrict__ srcU, const float* __restrict__ buU,
    const float* __restrict__ wtU, const float* __restrict__ bsU,
    const float* __restrict__ srcX, const float* __restrict__ buX,
    const float* __restrict__ wtX, const float* __restrict__ bsX,
    const float* __restrict__ srcD, const float* __restrict__ buD,
    const float* __restrict__ wtD, const float* __restrict__ bsD,
    float* __restrict__ dstU, float* __restrict__ dstX, float* __restrict__ dstD)
{
    __shared__ __align__(16) float bufA[SROWS * STRDQ];
    __shared__ __align__(16) float bufB[SROWS * STRDQ];

    const int tid = threadIdx.x;
    const int blk = blockIdx.x;

    const float* src; const float* BU; const float* wt; const float* bs;
    float* dst; int HW; int tx, ty, b;
    if (blk < 4096) {                 // up: 8 x (32 ty x 16 tx)
        src = srcU; BU = buU; wt = wtU; bs = bsU; dst = dstU; HW = 1024;
        b = blk >> 9; int rem = blk & 511; ty = rem >> 4; tx = rem & 15;
    } else if (blk < 5120) {          // x: 8 x (16 ty x 8 tx)
        int t = blk - 4096;
        src = srcX; BU = buX; wt = wtX; bs = bsX; dst = dstX; HW = 512;
        b = t >> 7; int rem = t & 127; ty = rem >> 3; tx = rem & 7;
    } else {                          // down: 8 x (8 ty x 4 tx)
        int t = blk - 5120;
        src = srcD; BU = buD; wt = wtD; bs = bsD; dst = dstD; HW = 256;
        b = t >> 5; int rem = t & 31; ty = rem >> 2; tx = rem & 3;
    }
    const int bh0 = ty * TH, bw0 = tx * TW;
    const long base = (long)b * HW * HW;

    // ---- stage: image rows -5..36, cols -8..71 -> bufA (img col c -> data quad (c+8)/4)
    for (int s = tid; s < SROWS * SQUADS; s += NTHR) {
        int r = s / SQUADS, cq = s - r * SQUADS;
        int gh = bh0 + r - 5;
        int gw = bw0 + (cq << 2) - 8;
        float4 v = {0.0f, 0.0f, 0.0f, 0.0f};
        if ((unsigned)gh < (unsigned)HW) {
            const float* gp = src + base + (long)gh * HW + gw;
            if (gw >= 0 && gw + 3 < HW) {
                v = *(const float4*)gp;
            } else {
                if ((unsigned)(gw + 0) < (unsigned)HW) v.x = gp[0];
                if ((unsigned)(gw + 1) < (unsigned)HW) v.y = gp[1];
                if ((unsigned)(gw + 2) < (unsigned)HW) v.z = gp[2];
                if ((unsigned)(gw + 3) < (unsigned)HW) v.w = gp[3];
            }
        }
        *(float4*)&bufA[lofs(r, cq)] = v;
    }
    // ---- zero bufB's never-written cells (rows {0,41} all quads; quads {0,19}
    // of rows 1..40): 120 quads, one wave-op round. Guarantees every LDS read
    // in the iteration loop returns finite data.
    for (int s = tid; s < 120; s += NTHR) {
        int r, q;
        if (s < 40)      { r = (s < 20) ? 0 : 41; q = s % 20; }
        else             { int s2 = s - 40; r = 1 + (s2 >> 1); q = (s2 & 1) ? 19 : 0; }
        float4 z = {0.0f, 0.0f, 0.0f, 0.0f};
        *(float4*)&bufB[lofs(r, q)] = z;
    }

    const float k00 = wt[0], k01 = wt[1], k02 = wt[2];
    const float k10 = wt[3], k11 = wt[4], k12 = wt[5];
    const float k20 = wt[6], k21 = wt[7], k22 = wt[8];
    const float bias = bs[0];

    // ---- strip assignment: thread t -> (t>>3)-th strip of bank-group
    // posmap[t&7] (balances the un-wrapped (2j+3rp) mod 8 component; see
    // lofs comment). Groups {0,1,3,6} have 23 strips, {2,4,5,7} have 22.
    // Within row-pair rp, strips of group g exist iff rp parity == g parity,
    // at j = j0 + 4*m (j0 = ((g-3rp)&7)>>1; m = 0..2 if j0==0 else 0..1).
    const bool act = (tid < NSTRIP);
    int rp = 0, j = 0;
    {
        int g = (0x75426310u >> ((tid & 7) << 2)) & 0xF;  // posmap {0,1,3,6,2,4,5,7}
        int need = tid >> 3;
        for (int r_ = (g & 1); r_ < 20; r_ += 2) {
            int j0 = ((g - 3 * r_) & 7) >> 1;             // 0..3
            int c = (j0 == 0) ? 3 : 2;
            if (need < c) { rp = r_; j = j0 + 4 * need; break; }
            need -= c;
        }
    }

    // precomputed swizzled LDS offsets (constant across all 5 iterations)
    int rdo[4][4];
    #pragma unroll
    for (int r = 0; r < 4; ++r)
        #pragma unroll
        for (int c = 0; c < 4; ++c)
            rdo[r][c] = lofs(2 * rp + r, 2 * j + c);
    int wro[2][2];
    #pragma unroll
    for (int i = 0; i < 2; ++i) {
        wro[i][0] = lofs(2 * rp + 1 + i, 2 * j + 1);
        wro[i][1] = lofs(2 * rp + 1 + i, 2 * j + 2);
    }

    // ---- premultiplied masks pm = hf(row-in-image) * wf(col-in-image)
    float4 pm0[2], pm1[2];
    float hf[2];
    #pragma unroll
    for (int i = 0; i < 2; ++i) {
        int gh = bh0 + 2 * rp - 4 + i;
        hf[i] = (act && (unsigned)gh < (unsigned)HW) ? 1.0f : 0.0f;
        float* p0 = (float*)&pm0[i]; float* p1 = (float*)&pm1[i];
        #pragma unroll
        for (int k = 0; k < 4; ++k) {
            p0[k] = hf[i] * (((unsigned)(bw0 + 8 * j - 4 + k) < (unsigned)HW) ? 1.0f : 0.0f);
            p1[k] = hf[i] * (((unsigned)(bw0 + 8 * j + k)     < (unsigned)HW) ? 1.0f : 0.0f);
        }
    }
    float4 bu0[2], bu1[2];            // (BU + bias), pre-masked 0 outside image
    #pragma unroll
    for (int i = 0; i < 2; ++i) {
        int gh = bh0 + 2 * rp - 4 + i;
        bool hok = (hf[i] != 0.0f);
        int gw0 = bw0 + 8 * j - 4;    // 4-aligned
        const float* bp = BU + base + (long)gh * HW + gw0;
        if (hok && gw0 >= 0 && gw0 + 7 < HW) {
            // interior fast path: two aligned float4 loads
            float4 a = *(const float4*)bp;
            float4 c = *(const float4*)(bp + 4);
            bu0[i] = {a.x + bias, a.y + bias, a.z + bias, a.w + bias};
            bu1[i] = {c.x + bias, c.y + bias, c.z + bias, c.w + bias};
        } else {
            float* b0 = (float*)&bu0[i]; float* b1 = (float*)&bu1[i];
            #pragma unroll
            for (int k = 0; k < 4; ++k) {
                int w0 = gw0 + k;
                int w1 = gw0 + 4 + k;
                b0[k] = (hok && (unsigned)w0 < (unsigned)HW) ? (bp[k] + bias)     : 0.0f;
                b1[k] = (hok && (unsigned)w1 < (unsigned)HW) ? (bp[k + 4] + bias) : 0.0f;
            }
        }
    }

    float* cur = bufA;
    float* nxt = bufB;

    for (int it = 0; it < 5; ++it) {
        __syncthreads();
        if (act) {
            float4 q[4][4];
            #pragma unroll
            for (int r = 0; r < 4; ++r)
                #pragma unroll
                for (int c = 0; c < 4; ++c)
                    q[r][c] = *(const float4*)(cur + rdo[r][c]);
            #pragma unroll
            for (int i = 0; i < 2; ++i) {
                float4 v0 = bu0[i];
                float4 v1 = bu1[i];
                acc_row(v0, q[i][0].w,     q[i][1],     q[i][2].x,     k00, k01, k02);
                acc_row(v0, q[i + 1][0].w, q[i + 1][1], q[i + 1][2].x, k10, k11, k12);
                acc_row(v0, q[i + 2][0].w, q[i + 2][1], q[i + 2][2].x, k20, k21, k22);
                acc_row(v1, q[i][1].w,     q[i][2],     q[i][3].x,     k00, k01, k02);
                acc_row(v1, q[i + 1][1].w, q[i + 1][2], q[i + 1][3].x, k10, k11, k12);
                acc_row(v1, q[i + 2][1].w, q[i + 2][2], q[i + 2][3].x, k20, k21, k22);
                clamp_mask(v0, pm0[i]);
                clamp_mask(v1, pm1[i]);
                *(float4*)(nxt + wro[i][0]) = v0;
                *(float4*)(nxt + wro[i][1]) = v1;
            }
        }
        float* t = cur; cur = nxt; nxt = t;
    }
    __syncthreads();

    // ---- store 64x32 interior (cur = bufB after 5 swaps): image (r,c) ->
    // row r+5, data quad (c+8)/4 -- all within the written region
    for (int i2 = tid; i2 < TH * (TW / 4); i2 += NTHR) {
        int r = i2 >> 4;
        int cq = i2 & 15;
        float4 v = *(const float4*)&cur[lofs(r + 5, cq + 2)];
        *(float4*)&dst[base + (long)(bh0 + r) * HW + bw0 + (cq << 2)] = v;
    }
}

// ---------------------------------------------------------------------------
// Cross-scale 1x1-conv fusion: one thread per down-level pixel; U/X/D read
// exactly once, all three outputs written.
// ---------------------------------------------------------------------------
__global__ __launch_bounds__(256) void fuse_all(
    const float* __restrict__ X,   // 8 x 512^2
    const float* __restrict__ D,   // 8 x 256^2
    const float* __restrict__ U,   // 8 x 1024^2
    const float* __restrict__ cx,
    const float* __restrict__ cd,
    const float* __restrict__ cu,
    float* __restrict__ xo, float* __restrict__ dno, float* __restrict__ upo)
{
    const int total = NBATCH << 16;  // 8*256*256
    int idx = blockIdx.x * blockDim.x + threadIdx.x;
    if (idx >= total) return;
    int wd = idx & 255;
    int hd = (idx >> 8) & 255;
    int b  = idx >> 16;

    const float cx0 = cx[0], cx1 = cx[1], cx2 = cx[2];
    const float cd0 = cd[0], cd1 = cd[1], cd2 = cd[2];
    const float cu0 = cu[0], cu1 = cu[1], cu2 = cu[2];

    int ub = (b << 20) + ((hd << 2) << 10) + (wd << 2);
    float4 u0 = *(const float4*)&U[ub];
    float4 u1 = *(const float4*)&U[ub + 1024];
    float4 u2 = *(const float4*)&U[ub + 2048];
    float4 u3 = *(const float4*)&U[ub + 3072];
    int xb = (b << 18) + ((hd << 1) << 9) + (wd << 1);
    float2 x0 = *(const float2*)&X[xb];
    float2 x1 = *(const float2*)&X[xb + 512];
    float dv = D[idx];

    float p00 = 0.25f * (u0.x + u0.y + u1.x + u1.y);
    float p01 = 0.25f * (u0.z + u0.w + u1.z + u1.w);
    float p10 = 0.25f * (u2.x + u2.y + u3.x + u3.y);
    float p11 = 0.25f * (u2.z + u2.w + u3.z + u3.w);
    float pu4 = 0.25f * (p00 + p01 + p10 + p11);
    float px2 = 0.25f * (x0.x + x0.y + x1.x + x1.y);

    dno[idx] = cd0 * pu4 + cd1 * px2 + cd2 * dv;

    float2 xo0, xo1;
    xo0.x = cx0 * p00 + cx1 * x0.x + cx2 * dv;
    xo0.y = cx0 * p01 + cx1 * x0.y + cx2 * dv;
    xo1.x = cx0 * p10 + cx1 * x1.x + cx2 * dv;
    xo1.y = cx0 * p11 + cx1 * x1.y + cx2 * dv;
    *(float2*)&xo[xb]       = xo0;
    *(float2*)&xo[xb + 512] = xo1;

    float4 o0, o1, o2, o3;
    o0.x = cu0 * u0.x + cu1 * x0.x + cu2 * dv;
    o0.y = cu0 * u0.y + cu1 * x0.x + cu2 * dv;
    o0.z = cu0 * u0.z + cu1 * x0.y + cu2 * dv;
    o0.w = cu0 * u0.w + cu1 * x0.y + cu2 * dv;
    o1.x = cu0 * u1.x + cu1 * x0.x + cu2 * dv;
    o1.y = cu0 * u1.y + cu1 * x0.x + cu2 * dv;
    o1.z = cu0 * u1.z + cu1 * x0.y + cu2 * dv;
    o1.w = cu0 * u1.w + cu1 * x0.y + cu2 * dv;
    o2.x = cu0 * u2.x + cu1 * x1.x + cu2 * dv;
    o2.y = cu0 * u2.y + cu1 * x1.x + cu2 * dv;
    o2.z = cu0 * u2.z + cu1 * x1.y + cu2 * dv;
    o2.w = cu0 * u2.w + cu1 * x1.y + cu2 * dv;
    o3.x = cu0 * u3.x + cu1 * x1.x + cu2 * dv;
    o3.y = cu0 * u3.y + cu1 * x1.x + cu2 * dv;
    o3.z = cu0 * u3.z + cu1 * x1.y + cu2 * dv;
    o3.w = cu0 * u3.w + cu1 * x1.y + cu2 * dv;
    *(float4*)&upo[ub]        = o0;
    *(float4*)&upo[ub + 1024] = o1;
    *(float4*)&upo[ub + 2048] = o2;
    *(float4*)&upo[ub + 3072] = o3;
}

// ---------------------------------------------------------------------------
extern "C" void kernel_launch(void* const* d_in, const int* in_sizes, int n_in,
                              void* d_out, int out_size, void* d_ws, size_t ws_size,
                              hipStream_t stream)
{
    const float* x    = (const float*)d_in[0];
    const float* down = (const float*)d_in[1];
    const float* up   = (const float*)d_in[2];
    const float* BUx  = (const float*)d_in[3];
    const float* BUd  = (const float*)d_in[4];
    const float* BUu  = (const float*)d_in[5];
    const float* wAx  = (const float*)d_in[6];
    const float* bx   = (const float*)d_in[7];
    const float* wAd  = (const float*)d_in[8];
    const float* bd   = (const float*)d_in[9];
    const float* wAu  = (const float*)d_in[10];
    const float* bu   = (const float*)d_in[11];
    const float* c1x  = (const float*)d_in[12];
    const float* c1d  = (const float*)d_in[13];
    const float* c1u  = (const float*)d_in[14];

    float* out = (float*)d_out;
    float* ws  = (float*)d_ws;

    const int NX = NBATCH * 512 * 512;
    const int ND = NBATCH * 256 * 256;

    float* wsX = ws;
    float* wsD = ws + NX;
    float* wsU = ws + NX + ND;
    float* outX = out;
    float* outD = out + NX;
    float* outU = out + NX + ND;

    // one dispatch, all levels: 4096 up + 1024 x + 256 down tiles (64x32 each)
    conv5_all<<<5376, NTHR, 0, stream>>>(
        up,   BUu, wAu, bu,
        x,    BUx, wAx, bx,
        down, BUd, wAd, bd,
        wsU, wsX, wsD);

    fuse_all<<<(ND + 255) / 256, 256, 0, stream>>>(wsX, wsD, wsU, c1x, c1d, c1u,
                                                   outX, outD, outU);
}